// Round 7
// baseline (194.290 us; speedup 1.0000x reference)
//
#include <hip/hip_runtime.h>
#include <stdint.h>

#define NUM_HEADS 12
#define DH 64
#define SEQ 2048
#define BATCH 2
#define DM 768
#define NQK 1536  // Q cols [0,768) | K cols [768,1536)
#define LOG2E 1.44269504088896340736f

typedef short short8 __attribute__((ext_vector_type(8)));
typedef short short4_t __attribute__((ext_vector_type(4)));
typedef float f32x4 __attribute__((ext_vector_type(4)));

__device__ __forceinline__ short bf16_rne(float f) {
    union { float f; uint32_t u; } v; v.f = f;
    return (short)((v.u + 0x7FFFu + ((v.u >> 16) & 1u)) >> 16);
}

// ---------------- Kernel 0: fused prep (wt | xb | mpack), branch on blockIdx ----------------
__global__ __launch_bounds__(256) void prep_kernel(const float* __restrict__ Wq,
                                                   const float* __restrict__ Wk,
                                                   const float* __restrict__ x,
                                                   const int* __restrict__ mask,
                                                   short* __restrict__ Wt,
                                                   short* __restrict__ Xb,
                                                   unsigned long long* __restrict__ Mb) {
    __shared__ float tile[32][33];
    const int bid = blockIdx.x;
    const int t = threadIdx.x;
    if (bid < 1152) {
        // ---- wt ----
        int n0 = (bid % 48) * 32;
        int k0 = (bid / 48) * 32;
        int tx = t & 31;
        int ty = t >> 5;
        const float* src = (n0 < DM) ? Wq : Wk;
        int nn0 = (n0 < DM) ? n0 : n0 - DM;
#pragma unroll
        for (int j = 0; j < 4; ++j) {
            int k = ty + 8 * j;
            tile[k][tx] = src[(size_t)(k0 + k) * DM + nn0 + tx];
        }
        __syncthreads();
#pragma unroll
        for (int j = 0; j < 4; ++j) {
            int n = ty + 8 * j;
            Wt[(size_t)(n0 + n) * DM + k0 + tx] = bf16_rne(tile[tx][n]);
        }
    } else if (bid < 1920) {
        // ---- xb ----
        size_t base = (size_t)(bid - 1152) * 4096;
#pragma unroll
        for (int j = 0; j < 4; ++j) {
            size_t i = base + (size_t)(t + j * 256) * 4;
            f32x4 v = *(const f32x4*)(x + i);
            short4_t s;
#pragma unroll
            for (int e = 0; e < 4; ++e) s[e] = bf16_rne(v[e]);
            *(short4_t*)(Xb + i) = s;
        }
    } else {
        // ---- mpack ----
        int wid = (bid - 1920) * 4 + (t >> 6);
        int lane = t & 63;
        size_t base = (size_t)wid * 8;
#pragma unroll
        for (int i = 0; i < 8; ++i) {
            size_t w = base + i;
            int v = mask[w * 64 + lane];
            unsigned long long bal = __ballot(v != 0);
            if (lane == 0) Mb[w] = bal;
        }
    }
}

// ---------------- Kernel 1: projection GEMM (128x128 tile, BK=64) ----------------
__global__ __launch_bounds__(256) void proj_kernel(const short* __restrict__ Xb,
                                                   const short* __restrict__ Wt,
                                                   const float* __restrict__ bq,
                                                   const float* __restrict__ bk,
                                                   short* __restrict__ QK) {
    __shared__ short As[128 * 72];
    __shared__ short Bs[128 * 72];
    const int m0 = blockIdx.x * 128;
    const int n0 = blockIdx.y * 128;
    const int t = threadIdx.x;
    const int lane = t & 63;
    const int w = t >> 6;
    const int wr = w >> 1, wc = w & 1;
    const int lr = lane & 15;
    const int lk = lane >> 4;

    f32x4 acc[4][4] = {};

    for (int k0 = 0; k0 < DM; k0 += 64) {
#pragma unroll
        for (int j = 0; j < 4; ++j) {
            int idx = t + 256 * j;
            int row = idx >> 3;
            int ch = idx & 7;
            *(short8*)&As[row * 72 + ch * 8] =
                *(const short8*)&Xb[(size_t)(m0 + row) * DM + k0 + ch * 8];
            *(short8*)&Bs[row * 72 + ch * 8] =
                *(const short8*)&Wt[(size_t)(n0 + row) * DM + k0 + ch * 8];
        }
        __syncthreads();
#pragma unroll
        for (int kk = 0; kk < 2; ++kk) {
            short8 a[4], bfr[4];
#pragma unroll
            for (int m = 0; m < 4; ++m)
                a[m] = *(short8*)&As[(wr * 64 + m * 16 + lr) * 72 + kk * 32 + lk * 8];
#pragma unroll
            for (int n = 0; n < 4; ++n)
                bfr[n] = *(short8*)&Bs[(wc * 64 + n * 16 + lr) * 72 + kk * 32 + lk * 8];
#pragma unroll
            for (int m = 0; m < 4; ++m)
#pragma unroll
                for (int n = 0; n < 4; ++n)
                    acc[m][n] = __builtin_amdgcn_mfma_f32_16x16x32_bf16(a[m], bfr[n], acc[m][n], 0, 0, 0);
        }
        __syncthreads();
    }

    const int orow = m0 + wr * 64;
    const int ocol = n0 + wc * 64;
#pragma unroll
    for (int m = 0; m < 4; ++m) {
#pragma unroll
        for (int n = 0; n < 4; ++n) {
            int col = ocol + n * 16 + lr;
            float bias = (col < DM) ? bq[col] : bk[col - DM];
            float scale = (col < DM) ? 0.125f * LOG2E : 1.0f;
#pragma unroll
            for (int r = 0; r < 4; ++r) {
                int row = orow + m * 16 + lk * 4 + r;
                QK[(size_t)row * NQK + col] = bf16_rne((acc[m][n][r] + bias) * scale);
            }
        }
    }
}

// ---------------- Kernel 2: single-pass attn, register-resident probs ----------------
// Block = 16 q rows; 4 waves split keys (wave w owns keys with (k>>6)&3==w).
// Swapped MFMA(K,Q): lane owns q = qblk*16 + (lane&15); per 64-key tile its 16 keys
// are nf*16 + lk*4 + r. Masked exp2 values live in e[8][4] f32x4 (128 VGPR).
__global__ __launch_bounds__(256, 2) void attn_kernel(const short* __restrict__ QK,
                                                      const unsigned long long* __restrict__ Mb,
                                                      float* __restrict__ out) {
    __shared__ short Ks[256 * 72];  // 256 keys x 64 dh (+8 pad)
    __shared__ float red[4][16];
    const int qblk = blockIdx.x;    // 0..127
    const int h = blockIdx.y;
    const int b = blockIdx.z;
    const int t = threadIdx.x;
    const int lane = t & 63;
    const int w = t >> 6;
    const int lr = lane & 15;
    const int lk = lane >> 4;
    const int q = qblk * 16 + lr;   // lane's q row

    // Q fragments (B-operand), pre-scaled by 0.125*log2e in projection
    const short8 aq0 = *(const short8*)&QK[(size_t)(b * SEQ + q) * NQK + h * DH + lk * 8];
    const short8 aq1 = *(const short8*)&QK[(size_t)(b * SEQ + q) * NQK + h * DH + 32 + lk * 8];

    const size_t mrow = (size_t)b * SEQ * (SEQ / 64) + (size_t)q * 32;
    const int sch = t & 7;          // staging: thread t -> rows (t>>3)+32j, chunk t&7

    f32x4 e[8][4];
    float lsum = 0.0f;

#pragma unroll
    for (int it = 0; it < 8; ++it) {
        const int kt0 = it * 256;
        // stage 256 keys cooperatively (fully coalesced 128B row-chunks)
#pragma unroll
        for (int j = 0; j < 8; ++j) {
            int row = (t >> 3) + 32 * j;
            *(short8*)&Ks[row * 72 + sch * 8] =
                *(const short8*)&QK[(size_t)(b * SEQ + kt0 + row) * NQK + DM + h * DH + sch * 8];
        }
        __syncthreads();
        const unsigned long long mbs = Mb[mrow + it * 4 + w] >> (lk * 4);
#pragma unroll
        for (int nf = 0; nf < 4; ++nf) {
            short8 k0 = *(short8*)&Ks[(w * 64 + nf * 16 + lr) * 72 + lk * 8];
            short8 k1 = *(short8*)&Ks[(w * 64 + nf * 16 + lr) * 72 + 32 + lk * 8];
            f32x4 a = {0.f, 0.f, 0.f, 0.f};
            a = __builtin_amdgcn_mfma_f32_16x16x32_bf16(k0, aq0, a, 0, 0, 0);
            a = __builtin_amdgcn_mfma_f32_16x16x32_bf16(k1, aq1, a, 0, 0, 0);
            f32x4 ev;
#pragma unroll
            for (int r = 0; r < 4; ++r) {
                float ex = __builtin_amdgcn_exp2f(a[r]);
                ev[r] = ((mbs >> (nf * 16 + r)) & 1ull) ? ex : 0.f;
                lsum += ev[r];
            }
            e[it][nf] = ev;
        }
        __syncthreads();
    }

    // ---- denominator: reduce over lk lanes, then over the 4 waves ----
    lsum += __shfl_xor(lsum, 16, 64);
    lsum += __shfl_xor(lsum, 32, 64);
    if (lane < 16) red[w][lr] = lsum;
    __syncthreads();
    const float inv = 1.0f / (red[0][lr] + red[1][lr] + red[2][lr] + red[3][lr]);

    // ---- scale + store (32 dwordx4 per lane) ----
    const size_t orow = ((size_t)((b * NUM_HEADS + h) * SEQ) + q) * SEQ;
#pragma unroll
    for (int it = 0; it < 8; ++it) {
#pragma unroll
        for (int nf = 0; nf < 4; ++nf) {
            f32x4 p;
#pragma unroll
            for (int r = 0; r < 4; ++r) p[r] = e[it][nf][r] * inv;
            *(f32x4*)&out[orow + it * 256 + w * 64 + nf * 16 + lk * 4] = p;
        }
    }
}

extern "C" void kernel_launch(void* const* d_in, const int* in_sizes, int n_in,
                              void* d_out, int out_size, void* d_ws, size_t ws_size,
                              hipStream_t stream) {
    (void)in_sizes; (void)n_in; (void)out_size; (void)ws_size;
    const float* x = (const float*)d_in[0];
    const int* mask = (const int*)d_in[1];
    const float* Wq = (const float*)d_in[2];
    const float* bq = (const float*)d_in[3];
    const float* Wk = (const float*)d_in[4];
    const float* bk = (const float*)d_in[5];
    float* out = (float*)d_out;

    short* Wt = (short*)d_ws;                           // 1536*768 bf16
    short* Xb = Wt + (size_t)NQK * DM;                  // 4096*768 bf16
    short* QK = Xb + (size_t)BATCH * SEQ * DM;          // 4096*1536 bf16
    unsigned long long* Mb =
        (unsigned long long*)(QK + (size_t)BATCH * SEQ * NQK);  // 131072 u64

    prep_kernel<<<dim3(6016), 256, 0, stream>>>(Wq, Wk, x, mask, Wt, Xb, Mb);
    proj_kernel<<<dim3(BATCH * SEQ / 128, NQK / 128), 256, 0, stream>>>(Xb, Wt, bq, bk, QK);
    attn_kernel<<<dim3(SEQ / 16, NUM_HEADS, BATCH), 256, 0, stream>>>(QK, Mb, out);
}